// Round 15
// baseline (23.471 us; speedup 1.0000x reference)
//
#include <hip/hip_runtime.h>
#include <math.h>

// ---------------------------------------------------------------------------
// Z_exp = Tr(M rho^x4) = degree-4 poly in Bloch (x,y,z), 35 monomials.
// R14 (16.6us): k-split chain, 13 barriers. R15: reduce stages FUSED into
// consumers via split-index-innermost partial layout (Pq[..][4], float4-
// contiguous -> 2x ds_read_b128 per operand sum) -> 8 barriers total;
// 1 element/thread -> 512 blocks (all CUs), shorter eval tail.
// Ascending-u inline sums keep results bit-identical to R14.
// ---------------------------------------------------------------------------

struct cpx { float re, im; };

__device__ __forceinline__ cpx cmul(cpx a, cpx b) {
    return { a.re * b.re - a.im * b.im, a.re * b.im + a.im * b.re };
}
__device__ __forceinline__ cpx cfma_(cpx acc, cpx a, cpx b) {
    acc.re += a.re * b.re - a.im * b.im;
    acc.im += a.re * b.im + a.im * b.re;
    return acc;
}
__device__ __forceinline__ cpx sum4(const cpx* p) {   // ascending order
    cpx s = p[0];
    s.re += p[1].re; s.im += p[1].im;
    s.re += p[2].re; s.im += p[2].im;
    s.re += p[3].re; s.im += p[3].im;
    return s;
}

// ---- compile-time Pauli-string -> monomial grouping (data-independent) ----
struct MonoTab { unsigned char cnt[125]; unsigned char idx[125][24]; };

constexpr int mono_of(int p) {
    int a = 0, b = 0, c = 0;
    for (int k = 0; k < 4; ++k) {
        const int pk = (p >> (2 * k)) & 3;   // 0=I,1=X,2=Y,3=Z
        a += (pk == 1); b += (pk == 2); c += (pk == 3);
    }
    return (a * 5 + b) * 5 + c;
}
constexpr MonoTab build_tab() {
    MonoTab t{};
    for (int m = 0; m < 125; ++m) {
        t.cnt[m] = 0;
        for (int k = 0; k < 24; ++k) t.idx[m][k] = 0;
    }
    for (int p = 0; p < 256; ++p) {          // ascending p: fixed sum order
        const int m = mono_of(p);
        t.idx[m][t.cnt[m]++] = (unsigned char)p;
    }
    return t;
}
__constant__ const MonoTab TAB = build_tab();

__global__ __launch_bounds__(1024) void fused_kernel(
    const float2* __restrict__ in2, const float* __restrict__ w_U,
    const float* __restrict__ w_RXZX, const float* __restrict__ scale_p,
    const float* __restrict__ bias_p, float* __restrict__ out, int B)
{
    __shared__ cpx   R[24][2][2];
    __shared__ float ISc[6], ISs[6];
    __shared__ cpx   L[6][16][16];
    __shared__ cpx   Pq[3][16][16][4];   // phase-3 partials, u innermost
    __shared__ cpx   Dq[16][16][4];
    __shared__ cpx   Wq[16][16][4];
    __shared__ cpx   Mq[16][16][4];
    __shared__ float cpp[256][4];
    __shared__ float cf[125];

    const int tid = threadIdx.x;
    const int idx = blockIdx.x * 1024 + tid;    // one element per thread
    const int q  = tid >> 8;                    // k-quarter 0..3
    const int ct = tid & 255;
    const int i = ct >> 4, j = ct & 15;
    const int k0 = q << 2;

    // ---- eval prep (all threads, before the chain) ----
    float2 f = { 0.f, 0.f };
    if (idx < B) f = in2[idx];
    const float scale = scale_p[0], bias = bias_p[0];
    float xp[5], yp[5], zp[5];
    {
        float s0, c0, s1, c1;
        sincosf(f.x, &s0, &c0);
        sincosf(f.y, &s1, &c1);
        const float x = s1 * c0, y = s1 * s0, z = c1;
        xp[0] = yp[0] = zp[0] = 1.f;
        #pragma unroll
        for (int k = 1; k < 5; ++k) {
            xp[k] = xp[k - 1] * x;
            yp[k] = yp[k - 1] * y;
            zp[k] = zp[k - 1] * z;
        }
    }

    // ---- Phase 1: 2x2 RXZX gates + iSWAP params ----
    if (tid < 24) {
        const float ta = w_RXZX[tid * 3 + 0];
        const float tb = w_RXZX[tid * 3 + 1];
        const float tc = w_RXZX[tid * 3 + 2];
        float sa, ca, sb, cb, sc, cc;
        sincosf(0.5f * ta, &sa, &ca);
        sincosf(0.5f * tb, &sb, &cb);
        sincosf(0.5f * tc, &sc, &cc);
        // RX(t)=[[c,-is],[-is,c]], RZ(t)=diag(c-is,c+is); g = RX(a)RZ(b)RX(c)
        const cpx e0 = { cb, -sb };
        const cpx e1 = { cb,  sb };
        const cpx T00 = { e0.re * cc, e0.im * cc };
        const cpx T01 = { -e0.im * (-sc), e0.re * (-sc) };
        const cpx T10 = { -e1.im * (-sc), e1.re * (-sc) };
        const cpx T11 = { e1.re * cc, e1.im * cc };
        R[tid][0][0] = { ca * T00.re + sa * T10.im, ca * T00.im - sa * T10.re };
        R[tid][0][1] = { ca * T01.re + sa * T11.im, ca * T01.im - sa * T11.re };
        R[tid][1][0] = { sa * T00.im + ca * T10.re, -sa * T00.re + ca * T10.im };
        R[tid][1][1] = { sa * T01.im + ca * T11.re, -sa * T01.re + ca * T11.im };
    } else if (tid < 30) {
        const int l = tid - 24;
        float s, c;
        sincosf(w_U[l], &s, &c);
        ISc[l] = c;
        ISs[l] = s;
    }
    __syncthreads();

    // ---- Phase 2: L[l] build; group q handles l = q, q+4 ----
    for (int l = q; l < 6; l += 4) {
        const int code = (int)((0xD89C8DC98DC9ULL >> (8 * l)) & 0xFF);
        const int qa = code & 3, qb = (code >> 2) & 3;
        const int qr = (code >> 4) & 3, qs = (code >> 6) & 3;
        const int uAi = (((i >> (3 - qa)) & 1) << 1) | ((i >> (3 - qb)) & 1);
        const int uAj = (((j >> (3 - qa)) & 1) << 1) | ((j >> (3 - qb)) & 1);
        const int uBi = (((i >> (3 - qr)) & 1) << 1) | ((i >> (3 - qs)) & 1);
        const int uBj = (((j >> (3 - qr)) & 1) << 1) | ((j >> (3 - qs)) & 1);
        const int ra = l * 4 + qa, rb = l * 4 + qb;
        cpx ga;
        if (uAj == 0)      ga = cmul(R[ra][uAi >> 1][0], R[rb][uAi & 1][0]);
        else if (uAj == 3) ga = cmul(R[ra][uAi >> 1][1], R[rb][uAi & 1][1]);
        else {
            const cpx k1 = cmul(R[ra][uAi >> 1][0], R[rb][uAi & 1][1]);
            const cpx k2 = cmul(R[ra][uAi >> 1][1], R[rb][uAi & 1][0]);
            const cpx tc = (uAj == 1) ? k1 : k2;   // * cos
            const cpx ts = (uAj == 1) ? k2 : k1;   // * i sin
            const float c = ISc[l], s = ISs[l];
            ga.re = c * tc.re - s * ts.im;
            ga.im = c * tc.im + s * ts.re;
        }
        const cpx gb = cmul(R[l * 4 + qr][uBi >> 1][uBj >> 1],
                            R[l * 4 + qs][uBi & 1][uBj & 1]);
        L[l][i][j] = cmul(ga, gb);
    }
    __syncthreads();

    // ---- Phase 3: quarter-k partials of the three pair products ----
    {
        cpx a0 = {0.f, 0.f}, a1 = {0.f, 0.f}, a2 = {0.f, 0.f};
        #pragma unroll
        for (int kk = 0; kk < 4; ++kk) {
            const int k = k0 + kk;
            a0 = cfma_(a0, L[1][i][k], L[0][k][j]);
            a1 = cfma_(a1, L[3][i][k], L[2][k][j]);
            a2 = cfma_(a2, L[5][i][k], L[4][k][j]);
        }
        Pq[0][i][j][q] = a0; Pq[1][i][j][q] = a1; Pq[2][i][j][q] = a2;
    }
    __syncthreads();

    // ---- Phase 4: D partial = quarter-k of P1[1]*P1[0] (inline sums) ----
    {
        cpx acc = {0.f, 0.f};
        #pragma unroll
        for (int kk = 0; kk < 4; ++kk) {
            const int k = k0 + kk;
            const cpx a = sum4(Pq[1][i][k]);
            const cpx b = sum4(Pq[0][k][j]);
            acc = cfma_(acc, a, b);
        }
        Dq[i][j][q] = acc;
    }
    __syncthreads();

    // ---- Phase 5: W partial = quarter-k of P1[2]*D ----
    {
        cpx acc = {0.f, 0.f};
        #pragma unroll
        for (int kk = 0; kk < 4; ++kk) {
            const int k = k0 + kk;
            const cpx a = sum4(Pq[2][i][k]);
            const cpx b = sum4(Dq[k][j]);
            acc = cfma_(acc, a, b);
        }
        Wq[i][j][q] = acc;
    }
    __syncthreads();

    // ---- Phase 6: M partial = quarter-k of sum_k zk conj(W[k][i])W[k][j] ----
    {
        cpx acc = {0.f, 0.f};
        #pragma unroll
        for (int kk = 0; kk < 4; ++kk) {
            const int k = k0 + kk;
            const float zk = (k < 8) ? 1.f : -1.f;
            const cpx a = sum4(Wq[k][i]);
            const cpx b = sum4(Wq[k][j]);
            acc.re += zk * (a.re * b.re + a.im * b.im);   // conj(a)*b
            acc.im += zk * (a.re * b.im - a.im * b.re);
        }
        Mq[i][j][q] = acc;
    }
    __syncthreads();

    // ---- Phase 7: Pauli-trace partials over col quarter (p = ct) ----
    {
        const int p = ct;
        float accre = 0.f;
        #pragma unroll
        for (int cc = 0; cc < 4; ++cc) {
            const int col = k0 + cc;
            int row = 0;
            cpx val = {1.f, 0.f};
            #pragma unroll
            for (int k = 0; k < 4; ++k) {
                const int pk = (p >> (6 - 2 * k)) & 3;
                const int b = (col >> (3 - k)) & 1;
                int rb = b;
                if (pk == 1) {
                    rb = b ^ 1;
                } else if (pk == 2) {
                    rb = b ^ 1;
                    const cpx fc = {0.f, b ? -1.f : 1.f};
                    val = cmul(val, fc);
                } else if (pk == 3) {
                    if (b) { val.re = -val.re; val.im = -val.im; }
                }
                row |= rb << (3 - k);
            }
            const cpx mv = sum4(Mq[col][row]);
            accre += mv.re * val.re - mv.im * val.im;
        }
        cpp[p][q] = accre;
    }
    __syncthreads();

    // ---- Phase 8: collapse (125 threads; per-p scale matches R14 order) ----
    if (tid < 125) {
        const int cnt = TAB.cnt[tid];
        float s = 0.f;
        for (int k = 0; k < cnt; ++k) {        // ascending: deterministic
            const float* v = cpp[TAB.idx[tid][k]];
            const float pv = (v[0] + v[1] + v[2] + v[3]) * (1.f / 16.f);
            s += pv;
        }
        cf[tid] = s;
    }
    __syncthreads();

    // ---- eval finish: 1 element per thread from LDS coefficients ----
    if (idx >= B) return;

    float Z = 0.f;
    #pragma unroll
    for (int a = 0; a <= 4; ++a)
        #pragma unroll
        for (int b = 0; b <= 4 - a; ++b)
            #pragma unroll
            for (int c = 0; c <= 4 - a - b; ++c)
                Z = fmaf(cf[(a * 5 + b) * 5 + c], xp[a] * yp[b] * zp[c], Z);

    const float noise = 0.04472135954999579f * (Z * Z - 1.f) * 0.25f;
    out[idx] = scale * (Z + noise) + bias;
}

extern "C" void kernel_launch(void* const* d_in, const int* in_sizes, int n_in,
                              void* d_out, int out_size, void* d_ws, size_t ws_size,
                              hipStream_t stream) {
    const float* inputs  = (const float*)d_in[0];   // [B,2] f32
    const float* w_U     = (const float*)d_in[1];   // [6]
    const float* w_RXZX  = (const float*)d_in[2];   // [6,4,3]
    const float* scale_p = (const float*)d_in[3];   // [1]
    const float* bias_p  = (const float*)d_in[4];   // [1]
    float* out = (float*)d_out;

    const int B = in_sizes[0] / 2;                  // elements
    const int nblocks = (B + 1023) / 1024;

    fused_kernel<<<nblocks, 1024, 0, stream>>>(
        (const float2*)inputs, w_U, w_RXZX, scale_p, bias_p, out, B);
}

// Round 16
// 21.000 us; speedup vs baseline: 1.1176x; 1.1176x over previous
//
#include <hip/hip_runtime.h>
#include <math.h>

// ---------------------------------------------------------------------------
// Z_exp = Tr(M rho^x4) = degree-4 poly in Bloch (x,y,z), 35 monomials.
// R14 (16.6us): 4-way k-split, 13 barrier phases (5 are reduces).
// R15 lesson: fusing reduces via redundant LDS sums REGRESSES (latency-bound:
// per-lane LDS ops are the cost). R16: reduce partials IN-REGISTER via
// __shfl_xor butterfly within a wave (wave = output row, lane = j*4+q).
// 8 barriers, per-phase LDS ops unchanged. [16][17] padding kills the
// 4-way bank aliasing of the q-split read pattern.
// ---------------------------------------------------------------------------

struct cpx { float re, im; };

__device__ __forceinline__ cpx cmul(cpx a, cpx b) {
    return { a.re * b.re - a.im * b.im, a.re * b.im + a.im * b.re };
}
__device__ __forceinline__ cpx cfma_(cpx acc, cpx a, cpx b) {
    acc.re += a.re * b.re - a.im * b.im;
    acc.im += a.re * b.im + a.im * b.re;
    return acc;
}
// butterfly over the q sub-lanes (lane bits 0..1): result (p0+p1)+(p2+p3),
// identical in all 4 lanes, deterministic.
__device__ __forceinline__ float bfly4(float v) {
    v += __shfl_xor(v, 1);
    v += __shfl_xor(v, 2);
    return v;
}
__device__ __forceinline__ cpx bfly4c(cpx v) {
    return { bfly4(v.re), bfly4(v.im) };
}

// ---- compile-time Pauli-string -> monomial grouping (data-independent) ----
struct MonoTab { unsigned char cnt[125]; unsigned char idx[125][24]; };

constexpr int mono_of(int p) {
    int a = 0, b = 0, c = 0;
    for (int k = 0; k < 4; ++k) {
        const int pk = (p >> (2 * k)) & 3;   // 0=I,1=X,2=Y,3=Z
        a += (pk == 1); b += (pk == 2); c += (pk == 3);
    }
    return (a * 5 + b) * 5 + c;
}
constexpr MonoTab build_tab() {
    MonoTab t{};
    for (int m = 0; m < 125; ++m) {
        t.cnt[m] = 0;
        for (int k = 0; k < 24; ++k) t.idx[m][k] = 0;
    }
    for (int p = 0; p < 256; ++p) {          // ascending p: fixed sum order
        const int m = mono_of(p);
        t.idx[m][t.cnt[m]++] = (unsigned char)p;
    }
    return t;
}
__constant__ const MonoTab TAB = build_tab();

__global__ __launch_bounds__(1024) void fused_kernel(
    const float2* __restrict__ in2, const float* __restrict__ w_U,
    const float* __restrict__ w_RXZX, const float* __restrict__ scale_p,
    const float* __restrict__ bias_p, float* __restrict__ out, int B)
{
    __shared__ cpx   R[24][2][2];
    __shared__ float ISc[6], ISs[6];
    __shared__ cpx   L[6][16][17];       // +1 pad: conflict-free q-split reads
    __shared__ cpx   P1[3][16][17];
    __shared__ cpx   Dm[16][17];
    __shared__ cpx   Wf[16][17];
    __shared__ cpx   Mm[16][17];
    __shared__ float cp[256];
    __shared__ float cf[125];

    const int tid  = threadIdx.x;
    const int idx  = blockIdx.x * 1024 + tid;   // one element per thread
    const int w    = tid >> 6;                  // wave = output row i
    const int lane = tid & 63;
    const int j    = lane >> 2;                 // output col
    const int q    = lane & 3;                  // k-quarter
    const int i    = w;
    const int k0   = q << 2;

    // ---- eval prep (all threads, before the chain) ----
    float2 f = { 0.f, 0.f };
    if (idx < B) f = in2[idx];
    const float scale = scale_p[0], bias = bias_p[0];
    float xp[5], yp[5], zp[5];
    {
        float s0, c0, s1, c1;
        sincosf(f.x, &s0, &c0);
        sincosf(f.y, &s1, &c1);
        const float x = s1 * c0, y = s1 * s0, z = c1;
        xp[0] = yp[0] = zp[0] = 1.f;
        #pragma unroll
        for (int k = 1; k < 5; ++k) {
            xp[k] = xp[k - 1] * x;
            yp[k] = yp[k - 1] * y;
            zp[k] = zp[k - 1] * z;
        }
    }

    // ---- Phase 1: 2x2 RXZX gates + iSWAP params ----
    if (tid < 24) {
        const float ta = w_RXZX[tid * 3 + 0];
        const float tb = w_RXZX[tid * 3 + 1];
        const float tc = w_RXZX[tid * 3 + 2];
        float sa, ca, sb, cb, sc, cc;
        sincosf(0.5f * ta, &sa, &ca);
        sincosf(0.5f * tb, &sb, &cb);
        sincosf(0.5f * tc, &sc, &cc);
        // RX(t)=[[c,-is],[-is,c]], RZ(t)=diag(c-is,c+is); g = RX(a)RZ(b)RX(c)
        const cpx e0 = { cb, -sb };
        const cpx e1 = { cb,  sb };
        const cpx T00 = { e0.re * cc, e0.im * cc };
        const cpx T01 = { -e0.im * (-sc), e0.re * (-sc) };
        const cpx T10 = { -e1.im * (-sc), e1.re * (-sc) };
        const cpx T11 = { e1.re * cc, e1.im * cc };
        R[tid][0][0] = { ca * T00.re + sa * T10.im, ca * T00.im - sa * T10.re };
        R[tid][0][1] = { ca * T01.re + sa * T11.im, ca * T01.im - sa * T11.re };
        R[tid][1][0] = { sa * T00.im + ca * T10.re, -sa * T00.re + ca * T10.im };
        R[tid][1][1] = { sa * T01.im + ca * T11.re, -sa * T01.re + ca * T11.im };
    } else if (tid < 30) {
        const int l = tid - 24;
        float s, c;
        sincosf(w_U[l], &s, &c);
        ISc[l] = c;
        ISs[l] = s;
    }
    __syncthreads();

    // ---- Phase 2: L[l] build; lane's q picks the layer (l=q, then l=q+4) ----
    for (int l = q; l < 6; l += 4) {
        const int code = (int)((0xD89C8DC98DC9ULL >> (8 * l)) & 0xFF);
        const int qa = code & 3, qb = (code >> 2) & 3;
        const int qr = (code >> 4) & 3, qs = (code >> 6) & 3;
        const int uAi = (((i >> (3 - qa)) & 1) << 1) | ((i >> (3 - qb)) & 1);
        const int uAj = (((j >> (3 - qa)) & 1) << 1) | ((j >> (3 - qb)) & 1);
        const int uBi = (((i >> (3 - qr)) & 1) << 1) | ((i >> (3 - qs)) & 1);
        const int uBj = (((j >> (3 - qr)) & 1) << 1) | ((j >> (3 - qs)) & 1);
        const int ra = l * 4 + qa, rb = l * 4 + qb;
        cpx ga;
        if (uAj == 0)      ga = cmul(R[ra][uAi >> 1][0], R[rb][uAi & 1][0]);
        else if (uAj == 3) ga = cmul(R[ra][uAi >> 1][1], R[rb][uAi & 1][1]);
        else {
            const cpx k1 = cmul(R[ra][uAi >> 1][0], R[rb][uAi & 1][1]);
            const cpx k2 = cmul(R[ra][uAi >> 1][1], R[rb][uAi & 1][0]);
            const cpx tc = (uAj == 1) ? k1 : k2;   // * cos
            const cpx ts = (uAj == 1) ? k2 : k1;   // * i sin
            const float c = ISc[l], s = ISs[l];
            ga.re = c * tc.re - s * ts.im;
            ga.im = c * tc.im + s * ts.re;
        }
        const cpx gb = cmul(R[l * 4 + qr][uBi >> 1][uBj >> 1],
                            R[l * 4 + qs][uBi & 1][uBj & 1]);
        L[l][i][j] = cmul(ga, gb);
    }
    __syncthreads();

    // ---- Phase 3: A=L1*L0, B=L3*L2, C=L5*L4 (quarter-k + shfl reduce) ----
    {
        cpx a0 = {0.f, 0.f}, a1 = {0.f, 0.f}, a2 = {0.f, 0.f};
        #pragma unroll
        for (int kk = 0; kk < 4; ++kk) {
            const int k = k0 + kk;
            a0 = cfma_(a0, L[1][i][k], L[0][k][j]);
            a1 = cfma_(a1, L[3][i][k], L[2][k][j]);
            a2 = cfma_(a2, L[5][i][k], L[4][k][j]);
        }
        a0 = bfly4c(a0); a1 = bfly4c(a1); a2 = bfly4c(a2);
        if (q == 0) {
            P1[0][i][j] = a0; P1[1][i][j] = a1; P1[2][i][j] = a2;
        }
    }
    __syncthreads();

    // ---- Phase 4: D = P1[1]*P1[0] ----
    {
        cpx acc = {0.f, 0.f};
        #pragma unroll
        for (int kk = 0; kk < 4; ++kk) {
            const int k = k0 + kk;
            acc = cfma_(acc, P1[1][i][k], P1[0][k][j]);
        }
        acc = bfly4c(acc);
        if (q == 0) Dm[i][j] = acc;
    }
    __syncthreads();

    // ---- Phase 5: W = P1[2]*D ----
    {
        cpx acc = {0.f, 0.f};
        #pragma unroll
        for (int kk = 0; kk < 4; ++kk) {
            const int k = k0 + kk;
            acc = cfma_(acc, P1[2][i][k], Dm[k][j]);
        }
        acc = bfly4c(acc);
        if (q == 0) Wf[i][j] = acc;
    }
    __syncthreads();

    // ---- Phase 6: M[i][j] = sum_k zk conj(W[k][i]) W[k][j] ----
    {
        cpx acc = {0.f, 0.f};
        #pragma unroll
        for (int kk = 0; kk < 4; ++kk) {
            const int k = k0 + kk;
            const float zk = (k < 8) ? 1.f : -1.f;
            const cpx a = Wf[k][i];
            const cpx b = Wf[k][j];
            acc.re += zk * (a.re * b.re + a.im * b.im);   // conj(a)*b
            acc.im += zk * (a.re * b.im - a.im * b.re);
        }
        acc = bfly4c(acc);
        if (q == 0) Mm[i][j] = acc;
    }
    __syncthreads();

    // ---- Phase 7: Pauli traces; p = w*16 + j, col quarter q ----
    {
        const int p = (w << 4) | j;
        float accre = 0.f;
        #pragma unroll
        for (int cc = 0; cc < 4; ++cc) {
            const int col = k0 + cc;
            int row = 0;
            cpx val = {1.f, 0.f};
            #pragma unroll
            for (int k = 0; k < 4; ++k) {
                const int pk = (p >> (6 - 2 * k)) & 3;
                const int b = (col >> (3 - k)) & 1;
                int rb = b;
                if (pk == 1) {
                    rb = b ^ 1;
                } else if (pk == 2) {
                    rb = b ^ 1;
                    const cpx fc = {0.f, b ? -1.f : 1.f};
                    val = cmul(val, fc);
                } else if (pk == 3) {
                    if (b) { val.re = -val.re; val.im = -val.im; }
                }
                row |= rb << (3 - k);
            }
            const cpx mv = Mm[col][row];
            accre += mv.re * val.re - mv.im * val.im;
        }
        accre = bfly4(accre);
        if (q == 0) cp[p] = accre * (1.f / 16.f);
    }
    __syncthreads();

    // ---- Phase 8: collapse via compile-time table ----
    if (tid < 125) {
        const int cnt = TAB.cnt[tid];
        float s = 0.f;
        for (int k = 0; k < cnt; ++k)          // ascending: deterministic
            s += cp[TAB.idx[tid][k]];
        cf[tid] = s;
    }
    __syncthreads();

    // ---- eval finish: 1 element per thread from LDS coefficients ----
    if (idx >= B) return;

    float Z = 0.f;
    #pragma unroll
    for (int a = 0; a <= 4; ++a)
        #pragma unroll
        for (int b = 0; b <= 4 - a; ++b)
            #pragma unroll
            for (int c = 0; c <= 4 - a - b; ++c)
                Z = fmaf(cf[(a * 5 + b) * 5 + c], xp[a] * yp[b] * zp[c], Z);

    const float noise = 0.04472135954999579f * (Z * Z - 1.f) * 0.25f;
    out[idx] = scale * (Z + noise) + bias;
}

extern "C" void kernel_launch(void* const* d_in, const int* in_sizes, int n_in,
                              void* d_out, int out_size, void* d_ws, size_t ws_size,
                              hipStream_t stream) {
    const float* inputs  = (const float*)d_in[0];   // [B,2] f32
    const float* w_U     = (const float*)d_in[1];   // [6]
    const float* w_RXZX  = (const float*)d_in[2];   // [6,4,3]
    const float* scale_p = (const float*)d_in[3];   // [1]
    const float* bias_p  = (const float*)d_in[4];   // [1]
    float* out = (float*)d_out;

    const int B = in_sizes[0] / 2;                  // elements
    const int nblocks = (B + 1023) / 1024;

    fused_kernel<<<nblocks, 1024, 0, stream>>>(
        (const float2*)inputs, w_U, w_RXZX, scale_p, bias_p, out, B);
}

// Round 17
// 16.662 us; speedup vs baseline: 1.4086x; 1.2603x over previous
//
#include <hip/hip_runtime.h>
#include <math.h>

// ---------------------------------------------------------------------------
// Z_exp = Tr(M rho^x4) = degree-4 poly in Bloch (x,y,z), 35 monomials.
// R14 (16.6us, best): 4-way k-split chain, 13 barrier phases.
// R15/R16 lessons: fusing reduces via extra LDS reads or shfl butterflies
// REGRESSES (latency-bound: per-lane DS ops are the cost).
// R17: (1) raw s_barrier with lgkmcnt(0)-only drain -- __syncthreads drains
// vmcnt(0) too, exposing the prefetched input load's HBM latency at the
// first barrier; LDS-only deps need only lgkmcnt (rule #18: sched_barrier
// after asm waitcnt). (2) 7b+8 fused via cpp[256][4] (b128-aligned) with
// R14's exact summation order. (3) eval trig prep moved after the chain.
// ---------------------------------------------------------------------------

struct cpx { float re, im; };

__device__ __forceinline__ cpx cmul(cpx a, cpx b) {
    return { a.re * b.re - a.im * b.im, a.re * b.im + a.im * b.re };
}
__device__ __forceinline__ cpx cfma_(cpx acc, cpx a, cpx b) {
    acc.re += a.re * b.re - a.im * b.im;
    acc.im += a.re * b.im + a.im * b.re;
    return acc;
}

// LDS-only barrier: wait own ds ops, pin order, barrier. No vmcnt drain ->
// the global prefetch stays in flight across the whole chain.
#define BAR() do { asm volatile("s_waitcnt lgkmcnt(0)" ::: "memory"); \
                   __builtin_amdgcn_sched_barrier(0);                 \
                   __builtin_amdgcn_s_barrier(); } while (0)

// ---- compile-time Pauli-string -> monomial grouping (data-independent) ----
struct MonoTab { unsigned char cnt[125]; unsigned char idx[125][24]; };

constexpr int mono_of(int p) {
    int a = 0, b = 0, c = 0;
    for (int k = 0; k < 4; ++k) {
        const int pk = (p >> (2 * k)) & 3;   // 0=I,1=X,2=Y,3=Z
        a += (pk == 1); b += (pk == 2); c += (pk == 3);
    }
    return (a * 5 + b) * 5 + c;
}
constexpr MonoTab build_tab() {
    MonoTab t{};
    for (int m = 0; m < 125; ++m) {
        t.cnt[m] = 0;
        for (int k = 0; k < 24; ++k) t.idx[m][k] = 0;
    }
    for (int p = 0; p < 256; ++p) {          // ascending p: fixed sum order
        const int m = mono_of(p);
        t.idx[m][t.cnt[m]++] = (unsigned char)p;
    }
    return t;
}
__constant__ const MonoTab TAB = build_tab();

__global__ __launch_bounds__(1024) void fused_kernel(
    const float4* __restrict__ in4, const float* __restrict__ w_U,
    const float* __restrict__ w_RXZX, const float* __restrict__ scale_p,
    const float* __restrict__ bias_p, float2* __restrict__ out2, int B2)
{
    __shared__ cpx   R[24][2][2];
    __shared__ float ISc[6], ISs[6];
    __shared__ cpx   L[6][16][16];
    __shared__ cpx   Pp[4][3][16][16];   // phase-3 partials (reused as PART)
    __shared__ cpx   P1[3][16][16];
    __shared__ cpx   Dm[16][16];
    __shared__ cpx   Wf[16][16];
    __shared__ cpx   Mm[16][16];
    __shared__ float cpp[256][4];        // trace partials, q innermost (b128)
    __shared__ float cf[125];

    cpx (*PART)[16][16] = (cpx(*)[16][16])Pp;   // reuse Pp after phase 3b

    const int tid = threadIdx.x;
    const int idx = blockIdx.x * 1024 + tid;    // float4 unit (2 elements)
    const int q  = tid >> 8;                    // k-quarter 0..3
    const int ct = tid & 255;
    const int i = ct >> 4, j = ct & 15;
    const int k0 = q << 2;

    // prefetch only (latency hidden under the whole chain; no vmcnt drain)
    float4 f = make_float4(0.f, 0.f, 0.f, 0.f);
    if (idx < B2) f = in4[idx];

    // ---- Phase 1: 2x2 RXZX gates + iSWAP params ----
    if (tid < 24) {
        const float ta = w_RXZX[tid * 3 + 0];
        const float tb = w_RXZX[tid * 3 + 1];
        const float tc = w_RXZX[tid * 3 + 2];
        float sa, ca, sb, cb, sc, cc;
        sincosf(0.5f * ta, &sa, &ca);
        sincosf(0.5f * tb, &sb, &cb);
        sincosf(0.5f * tc, &sc, &cc);
        // RX(t)=[[c,-is],[-is,c]], RZ(t)=diag(c-is,c+is); g = RX(a)RZ(b)RX(c)
        const cpx e0 = { cb, -sb };
        const cpx e1 = { cb,  sb };
        const cpx T00 = { e0.re * cc, e0.im * cc };
        const cpx T01 = { -e0.im * (-sc), e0.re * (-sc) };
        const cpx T10 = { -e1.im * (-sc), e1.re * (-sc) };
        const cpx T11 = { e1.re * cc, e1.im * cc };
        R[tid][0][0] = { ca * T00.re + sa * T10.im, ca * T00.im - sa * T10.re };
        R[tid][0][1] = { ca * T01.re + sa * T11.im, ca * T01.im - sa * T11.re };
        R[tid][1][0] = { sa * T00.im + ca * T10.re, -sa * T00.re + ca * T10.im };
        R[tid][1][1] = { sa * T01.im + ca * T11.re, -sa * T01.re + ca * T11.im };
    } else if (tid < 30) {
        const int l = tid - 24;
        float s, c;
        sincosf(w_U[l], &s, &c);
        ISc[l] = c;
        ISs[l] = s;
    }
    BAR();

    // ---- Phase 2: L[l] build; group q handles l = q, q+4 ----
    for (int l = q; l < 6; l += 4) {
        const int code = (int)((0xD89C8DC98DC9ULL >> (8 * l)) & 0xFF);
        const int qa = code & 3, qb = (code >> 2) & 3;
        const int qr = (code >> 4) & 3, qs = (code >> 6) & 3;
        const int uAi = (((i >> (3 - qa)) & 1) << 1) | ((i >> (3 - qb)) & 1);
        const int uAj = (((j >> (3 - qa)) & 1) << 1) | ((j >> (3 - qb)) & 1);
        const int uBi = (((i >> (3 - qr)) & 1) << 1) | ((i >> (3 - qs)) & 1);
        const int uBj = (((j >> (3 - qr)) & 1) << 1) | ((j >> (3 - qs)) & 1);
        const int ra = l * 4 + qa, rb = l * 4 + qb;
        cpx ga;
        if (uAj == 0)      ga = cmul(R[ra][uAi >> 1][0], R[rb][uAi & 1][0]);
        else if (uAj == 3) ga = cmul(R[ra][uAi >> 1][1], R[rb][uAi & 1][1]);
        else {
            const cpx k1 = cmul(R[ra][uAi >> 1][0], R[rb][uAi & 1][1]);
            const cpx k2 = cmul(R[ra][uAi >> 1][1], R[rb][uAi & 1][0]);
            const cpx tc = (uAj == 1) ? k1 : k2;   // * cos
            const cpx ts = (uAj == 1) ? k2 : k1;   // * i sin
            const float c = ISc[l], s = ISs[l];
            ga.re = c * tc.re - s * ts.im;
            ga.im = c * tc.im + s * ts.re;
        }
        const cpx gb = cmul(R[l * 4 + qr][uBi >> 1][uBj >> 1],
                            R[l * 4 + qs][uBi & 1][uBj & 1]);
        L[l][i][j] = cmul(ga, gb);
    }
    BAR();

    // ---- Phase 3: Pp[q][m] = quarter-k partial of L[2m+1]*L[2m] ----
    {
        cpx a0 = {0.f, 0.f}, a1 = {0.f, 0.f}, a2 = {0.f, 0.f};
        #pragma unroll
        for (int kk = 0; kk < 4; ++kk) {
            const int k = k0 + kk;
            a0 = cfma_(a0, L[1][i][k], L[0][k][j]);
            a1 = cfma_(a1, L[3][i][k], L[2][k][j]);
            a2 = cfma_(a2, L[5][i][k], L[4][k][j]);
        }
        Pp[q][0][i][j] = a0; Pp[q][1][i][j] = a1; Pp[q][2][i][j] = a2;
    }
    BAR();

    // ---- Phase 3b: reduce 4 partials (768 items, ascending q order) ----
    if (tid < 768) {
        const int m = tid >> 8, e = tid & 255, i2 = e >> 4, j2 = e & 15;
        cpx s = Pp[0][m][i2][j2];
        #pragma unroll
        for (int u = 1; u < 4; ++u) {
            const cpx t = Pp[u][m][i2][j2];
            s.re += t.re; s.im += t.im;
        }
        P1[m][i2][j2] = s;
    }
    BAR();

    // ---- Phase 4: PART[q] = quarter-k partial of P1[1]*P1[0] ----
    {
        cpx acc = {0.f, 0.f};
        #pragma unroll
        for (int kk = 0; kk < 4; ++kk) {
            const int k = k0 + kk;
            acc = cfma_(acc, P1[1][i][k], P1[0][k][j]);
        }
        PART[q][i][j] = acc;
    }
    BAR();
    if (tid < 256) {
        cpx s = PART[0][i][j];
        #pragma unroll
        for (int u = 1; u < 4; ++u) {
            const cpx t = PART[u][i][j];
            s.re += t.re; s.im += t.im;
        }
        Dm[i][j] = s;
    }
    BAR();

    // ---- Phase 5: W = P1[2]*D (same split) ----
    {
        cpx acc = {0.f, 0.f};
        #pragma unroll
        for (int kk = 0; kk < 4; ++kk) {
            const int k = k0 + kk;
            acc = cfma_(acc, P1[2][i][k], Dm[k][j]);
        }
        PART[q][i][j] = acc;
    }
    BAR();
    if (tid < 256) {
        cpx s = PART[0][i][j];
        #pragma unroll
        for (int u = 1; u < 4; ++u) {
            const cpx t = PART[u][i][j];
            s.re += t.re; s.im += t.im;
        }
        Wf[i][j] = s;
    }
    BAR();

    // ---- Phase 6: M[i][j] = sum_k zk conj(W[k][i]) W[k][j] (same split) ----
    {
        cpx acc = {0.f, 0.f};
        #pragma unroll
        for (int kk = 0; kk < 4; ++kk) {
            const int k = k0 + kk;
            const float zk = (k < 8) ? 1.f : -1.f;
            const cpx a = Wf[k][i];
            const cpx b = Wf[k][j];
            acc.re += zk * (a.re * b.re + a.im * b.im);   // conj(a)*b
            acc.im += zk * (a.re * b.im - a.im * b.re);
        }
        PART[q][i][j] = acc;
    }
    BAR();
    if (tid < 256) {
        cpx s = PART[0][i][j];
        #pragma unroll
        for (int u = 1; u < 4; ++u) {
            const cpx t = PART[u][i][j];
            s.re += t.re; s.im += t.im;
        }
        Mm[i][j] = s;
    }
    BAR();

    // ---- Phase 7: Pauli-trace partials over col quarter (p = ct) ----
    {
        const int p = ct;
        float accre = 0.f;
        #pragma unroll
        for (int cc = 0; cc < 4; ++cc) {
            const int col = k0 + cc;
            int row = 0;
            cpx val = {1.f, 0.f};
            #pragma unroll
            for (int k = 0; k < 4; ++k) {
                const int pk = (p >> (6 - 2 * k)) & 3;
                const int b = (col >> (3 - k)) & 1;
                int rb = b;
                if (pk == 1) {
                    rb = b ^ 1;
                } else if (pk == 2) {
                    rb = b ^ 1;
                    const cpx fc = {0.f, b ? -1.f : 1.f};
                    val = cmul(val, fc);
                } else if (pk == 3) {
                    if (b) { val.re = -val.re; val.im = -val.im; }
                }
                row |= rb << (3 - k);
            }
            const cpx mv = Mm[col][row];
            accre += mv.re * val.re - mv.im * val.im;
        }
        cpp[p][q] = accre;
    }
    BAR();

    // ---- Phase 7b+8 fused: collapse with inline 4-partial sums (b128) ----
    if (tid < 125) {
        const int cnt = TAB.cnt[tid];
        float s = 0.f;
        for (int k = 0; k < cnt; ++k) {        // ascending: deterministic
            const float* v = cpp[TAB.idx[tid][k]];
            s += (v[0] + v[1] + v[2] + v[3]) * (1.f / 16.f);
        }
        cf[tid] = s;
    }
    BAR();

    // ---- eval: prep + 2 elements per thread from LDS coefficients ----
    if (idx >= B2) return;
    const float scale = scale_p[0], bias = bias_p[0];

    float2 res;
    #pragma unroll
    for (int e = 0; e < 2; ++e) {
        const float f0 = e ? f.z : f.x;    // vmcnt waited here, fully hidden
        const float f1 = e ? f.w : f.y;
        float s0, c0, s1, c1;
        sincosf(f0, &s0, &c0);
        sincosf(f1, &s1, &c1);
        const float x = s1 * c0, y = s1 * s0, z = c1;

        float xp[5], yp[5], zp[5];
        xp[0] = yp[0] = zp[0] = 1.f;
        #pragma unroll
        for (int k = 1; k < 5; ++k) {
            xp[k] = xp[k - 1] * x;
            yp[k] = yp[k - 1] * y;
            zp[k] = zp[k - 1] * z;
        }

        float Z = 0.f;
        #pragma unroll
        for (int a = 0; a <= 4; ++a)
            #pragma unroll
            for (int b = 0; b <= 4 - a; ++b)
                #pragma unroll
                for (int c = 0; c <= 4 - a - b; ++c)
                    Z = fmaf(cf[(a * 5 + b) * 5 + c], xp[a] * yp[b] * zp[c], Z);

        const float noise = 0.04472135954999579f * (Z * Z - 1.f) * 0.25f;
        const float v = scale * (Z + noise) + bias;
        if (e) res.y = v; else res.x = v;
    }
    out2[idx] = res;
}

extern "C" void kernel_launch(void* const* d_in, const int* in_sizes, int n_in,
                              void* d_out, int out_size, void* d_ws, size_t ws_size,
                              hipStream_t stream) {
    const float* inputs  = (const float*)d_in[0];   // [B,2] f32
    const float* w_U     = (const float*)d_in[1];   // [6]
    const float* w_RXZX  = (const float*)d_in[2];   // [6,4,3]
    const float* scale_p = (const float*)d_in[3];   // [1]
    const float* bias_p  = (const float*)d_in[4];   // [1]
    float* out = (float*)d_out;

    const int B  = in_sizes[0] / 2;                 // elements
    const int B2 = B / 2;                           // float4 units (2 el/thr)
    const int nblocks = (B2 + 1023) / 1024;

    fused_kernel<<<nblocks, 1024, 0, stream>>>(
        (const float4*)inputs, w_U, w_RXZX, scale_p, bias_p, (float2*)out, B2);
}